// Round 4
// baseline (237.869 us; speedup 1.0000x reference)
//
#include <hip/hip_runtime.h>

#define NVEC (64*64*64)   // 262144 vectors
#define KCB 1024          // codebook size
#define DIM 64            // codebook dim

typedef __attribute__((ext_vector_type(8))) short s16x8;   // 8 x bf16
typedef __attribute__((ext_vector_type(4))) float f32x4;

#define MFMA16(A, B, C) __builtin_amdgcn_mfma_f32_16x16x32_bf16((A), (B), (C), 0, 0, 0)

// ws layout (bytes):
//      0 : double loss_sum
//      8 : uint counts[1024]            (ends 4104, pad 4112)
//   4112 : float cnf[1024]              (ends 8208, pad 8224)
//   8224 : ushort cbA[64][2][64][8]     A-fragment layout of bf16(-2c), 131072 B, ends 139296

__global__ __launch_bounds__(256) void vq_prep(const float* __restrict__ cb,
                                               unsigned short* __restrict__ cbA,
                                               float* __restrict__ cnf) {
    int q = blockIdx.x * 256 + threadIdx.x;      // 0..8191
    int t = q >> 7;                               // code tile 0..63
    int h = (q >> 6) & 1;                         // k-half 0..1
    int l = q & 63;                               // lane slot
    int m = t * 16 + (l & 15);                    // code row
    int d0 = h * 32 + ((l >> 4) & 3) * 8;         // first dim of this lane's 8
    const float* row = cb + (size_t)m * DIM + d0;
    unsigned short* dst = cbA + (size_t)q * 8;
    #pragma unroll
    for (int j = 0; j < 8; ++j) {
        float f = -2.0f * row[j];
        unsigned u = __float_as_uint(f);
        dst[j] = (unsigned short)((u + 0x7fffu + ((u >> 16) & 1u)) >> 16);  // RNE bf16
    }
    if (q < KCB) {
        const float* r2 = cb + (size_t)q * DIM;
        double s = 0.0;
        for (int d = 0; d < DIM; ++d) { double c = (double)r2[d]; s = fma(c, c, s); }
        cnf[q] = (float)s;
    }
}

__global__ __launch_bounds__(256, 6) void vq_main(const float* __restrict__ inp,
                                                  const unsigned short* __restrict__ cbA,
                                                  const float* __restrict__ cnf,
                                                  const float* __restrict__ cb,
                                                  float* __restrict__ out,
                                                  double* __restrict__ loss_sum,
                                                  unsigned int* __restrict__ counts) {
    const int tid  = threadIdx.x;
    const int lane = tid & 63;
    const int w    = tid >> 6;
    const int pair = w >> 1;          // 0,1 : which 64-vector set of this block
    const int wip  = w & 1;           // 0,1 : which codebook half this wave sweeps
    const int l15  = lane & 15;
    const int g    = lane >> 4;
    const int gi   = g * 4;
    const int vecbase = blockIdx.x * 128 + pair * 64;

    // ---- load the pair's 64 vectors, convert to bf16 B-frags, accumulate ||x||^2 ----
    // B[k][n]: lane l holds n=l&15, k=(l>>4)*8+j; half h covers dims h*32..h*32+31
    s16x8 xb[4][2];
    float xnorm[4];
    #pragma unroll
    for (int v = 0; v < 4; ++v) {
        const float4* xp = (const float4*)(inp + (size_t)(vecbase + v * 16 + l15) * DIM);
        float4 a0 = xp[g * 2], a1 = xp[g * 2 + 1];
        float4 a2 = xp[8 + g * 2], a3 = xp[8 + g * 2 + 1];
        float f0[8] = {a0.x, a0.y, a0.z, a0.w, a1.x, a1.y, a1.z, a1.w};
        float f1[8] = {a2.x, a2.y, a2.z, a2.w, a3.x, a3.y, a3.z, a3.w};
        float xn = 0.f;
        unsigned w0[4], w1[4];
        #pragma unroll
        for (int p = 0; p < 4; ++p) {
            xn = fmaf(f0[2*p], f0[2*p], xn);
            xn = fmaf(f0[2*p+1], f0[2*p+1], xn);
            xn = fmaf(f1[2*p], f1[2*p], xn);
            xn = fmaf(f1[2*p+1], f1[2*p+1], xn);
            unsigned r0, r1;
            asm("v_cvt_pk_bf16_f32 %0, %1, %2" : "=v"(r0) : "v"(f0[2*p]), "v"(f0[2*p+1]));
            asm("v_cvt_pk_bf16_f32 %0, %1, %2" : "=v"(r1) : "v"(f1[2*p]), "v"(f1[2*p+1]));
            w0[p] = r0; w1[p] = r1;
        }
        xb[v][0] = *(const s16x8*)w0;
        xb[v][1] = *(const s16x8*)w1;
        xnorm[v] = xn;
    }

    float best[4] = {3.4e38f, 3.4e38f, 3.4e38f, 3.4e38f};

    // ---- K sweep: this wave covers codes [wip*512, wip*512+512) = 32 tiles ----
    const s16x8* Ap  = (const s16x8*)cbA + (size_t)(wip * 64) * 64 + lane;
    const float* cnp = cnf + wip * 512 + gi;

    #pragma unroll 2
    for (int t = 0; t < 32; ++t) {
        s16x8 A0 = Ap[0];
        s16x8 A1 = Ap[64];
        f32x4 cn4 = *(const f32x4*)cnp;      // acc init = ||c||^2

        f32x4 acc[4];
        #pragma unroll
        for (int v = 0; v < 4; ++v) acc[v] = cn4;
        #pragma unroll
        for (int v = 0; v < 4; ++v) acc[v] = MFMA16(A0, xb[v][0], acc[v]);
        #pragma unroll
        for (int v = 0; v < 4; ++v) acc[v] = MFMA16(A1, xb[v][1], acc[v]);

        int kb = wip * 512 + (t << 4) + gi;  // code index base for this lane-group
        #pragma unroll
        for (int v = 0; v < 4; ++v) {
            unsigned p0 = (__float_as_uint(acc[v][0]) & 0xFFFFFC00u) | (unsigned)(kb);
            unsigned p1 = (__float_as_uint(acc[v][1]) & 0xFFFFFC00u) | (unsigned)(kb + 1);
            unsigned p2 = (__float_as_uint(acc[v][2]) & 0xFFFFFC00u) | (unsigned)(kb + 2);
            unsigned p3 = (__float_as_uint(acc[v][3]) & 0xFFFFFC00u) | (unsigned)(kb + 3);
            // nested mins -> v_min3 fusion
            best[v] = fminf(fminf(best[v], __uint_as_float(p0)),
                            fminf(fminf(__uint_as_float(p1), __uint_as_float(p2)),
                                  __uint_as_float(p3)));
        }
        Ap  += 128;
        cnp += 16;
    }

    // ---- reduce across the 4 lane groups; also finish ||x||^2 ----
    #pragma unroll
    for (int v = 0; v < 4; ++v) {
        best[v] = fminf(best[v], __shfl_xor(best[v], 16));
        best[v] = fminf(best[v], __shfl_xor(best[v], 32));
        xnorm[v] += __shfl_xor(xnorm[v], 16);
        xnorm[v] += __shfl_xor(xnorm[v], 32);
    }

    // ---- combine the two codebook halves across the wave pair via LDS ----
    __shared__ float sb[2][2][4][16];
    if (lane < 16) {
        #pragma unroll
        for (int v = 0; v < 4; ++v) sb[pair][wip][v][lane] = best[v];
    }
    __syncthreads();
    int bidx[4];
    #pragma unroll
    for (int v = 0; v < 4; ++v) {
        best[v] = fminf(best[v], sb[pair][wip ^ 1][v][l15]);
        bidx[v] = (int)(__float_as_uint(best[v]) & 1023u);
    }

    // ---- epilogue, split across the pair: wave wip owns v = wip*2, wip*2+1 ----
    float4* ob4 = (float4*)(out + (size_t)vecbase * DIM);
    float ls = 0.0f;
    #pragma unroll
    for (int vv = 0; vv < 2; ++vv) {
        int v = wip * 2 + vv;
        #pragma unroll
        for (int i = 0; i < 4; ++i) {
            int wv = i * 4 + g;
            int bk = __shfl(bidx[v], wv);
            float4 q = ((const float4*)(cb + (size_t)bk * DIM))[l15];
            ob4[(v * 16 + wv) * 16 + l15] = q;
        }
        if (g == 0) {
            atomicAdd(&counts[bidx[v]], 1u);
            ls += best[v] + xnorm[v];    // min distance = score + ||x||^2 (err ~1e-6)
        }
    }
    double dsum = (double)ls;
    #pragma unroll
    for (int off = 32; off > 0; off >>= 1) dsum += __shfl_xor(dsum, off);
    if (lane == 0) atomicAdd(loss_sum, dsum);
}

__global__ __launch_bounds__(256) void vq_finalize(float* __restrict__ out,
                                                   const double* __restrict__ loss_sum,
                                                   const unsigned int* __restrict__ counts) {
    __shared__ double red[256];
    double h = 0.0;
    for (int k = threadIdx.x; k < KCB; k += 256) {
        double p = (double)counts[k] / (double)NVEC;
        h += p * log(p + 1e-10);
    }
    red[threadIdx.x] = h;
    __syncthreads();
    for (int s = 128; s > 0; s >>= 1) {
        if (threadIdx.x < s) red[threadIdx.x] += red[threadIdx.x + s];
        __syncthreads();
    }
    if (threadIdx.x == 0) {
        out[(size_t)NVEC * DIM]     = (float)(0.25 * (*loss_sum) / (double)((size_t)NVEC * DIM));
        out[(size_t)NVEC * DIM + 1] = (float)exp(-red[0]);
    }
}

extern "C" void kernel_launch(void* const* d_in, const int* in_sizes, int n_in,
                              void* d_out, int out_size, void* d_ws, size_t ws_size,
                              hipStream_t stream) {
    const float* inp = (const float*)d_in[0];   // (64,64,64,64) f32
    const float* cb  = (const float*)d_in[1];   // (1024,64) f32
    float* out = (float*)d_out;

    char* ws = (char*)d_ws;
    double*         loss_sum = (double*)(ws + 0);
    unsigned int*   counts   = (unsigned int*)(ws + 8);
    float*          cnf      = (float*)(ws + 4112);
    unsigned short* cbA      = (unsigned short*)(ws + 8224);

    hipMemsetAsync(ws, 0, 4112, stream);
    vq_prep<<<dim3(32), dim3(256), 0, stream>>>(cb, cbA, cnf);
    vq_main<<<dim3(NVEC / 128), dim3(256), 0, stream>>>(inp, cbA, cnf, cb, out,
                                                        loss_sum, counts);
    vq_finalize<<<dim3(1), dim3(256), 0, stream>>>(out, loss_sum, counts);
}

// Round 5
// 206.324 us; speedup vs baseline: 1.1529x; 1.1529x over previous
//
#include <hip/hip_runtime.h>

#define NVEC (64*64*64)   // 262144 vectors
#define KCB 1024          // codebook size
#define DIM 64            // codebook dim

typedef __attribute__((ext_vector_type(8))) short s16x8;   // 8 x bf16
typedef __attribute__((ext_vector_type(4))) float f32x4;

#define MFMA16(A, B, C) __builtin_amdgcn_mfma_f32_16x16x32_bf16((A), (B), (C), 0, 0, 0)

// ws layout (bytes):
//      0 : double loss_sum
//      8 : uint counts[1024]            (ends 4104, pad 4112)
//   4112 : float cnf[1024]              (ends 8208, pad 8224)
//   8224 : ushort cbA[64][2][64][8]     A-fragment layout of bf16(-2c), 131072 B, ends 139296

__global__ __launch_bounds__(256) void vq_prep(const float* __restrict__ cb,
                                               unsigned short* __restrict__ cbA,
                                               float* __restrict__ cnf) {
    int q = blockIdx.x * 256 + threadIdx.x;      // 0..8191
    int t = q >> 7;                               // code tile 0..63
    int h = (q >> 6) & 1;                         // k-half 0..1
    int l = q & 63;                               // lane slot
    int m = t * 16 + (l & 15);                    // code row
    int d0 = h * 32 + ((l >> 4) & 3) * 8;         // first dim of this lane's 8
    const float* row = cb + (size_t)m * DIM + d0;
    unsigned short* dst = cbA + (size_t)q * 8;
    #pragma unroll
    for (int j = 0; j < 8; ++j) {
        float f = -2.0f * row[j];
        unsigned u = __float_as_uint(f);
        dst[j] = (unsigned short)((u + 0x7fffu + ((u >> 16) & 1u)) >> 16);  // RNE bf16
    }
    if (q < KCB) {
        const float* r2 = cb + (size_t)q * DIM;
        double s = 0.0;
        for (int d = 0; d < DIM; ++d) { double c = (double)r2[d]; s = fma(c, c, s); }
        cnf[q] = (float)s;
    }
}

__global__ __launch_bounds__(256) void vq_main(const float* __restrict__ inp,
                                               const unsigned short* __restrict__ cbA,
                                               const float* __restrict__ cnf,
                                               const float* __restrict__ cb,
                                               float* __restrict__ out,
                                               double* __restrict__ loss_sum,
                                               unsigned int* __restrict__ counts) {
    const int tid  = threadIdx.x;
    const int lane = tid & 63;
    const int w    = tid >> 6;
    const int pair = w >> 1;          // 0,1 : which 64-vector set of this block
    const int wip  = w & 1;           // 0,1 : which codebook half this wave sweeps
    const int l15  = lane & 15;
    const int g    = lane >> 4;
    const int gi   = g * 4;
    const int vecbase = blockIdx.x * 128 + pair * 64;

    // ---- load the pair's 64 vectors, convert to bf16 B-frags, accumulate ||x||^2 ----
    // B[k][n]: lane l holds n=l&15, k=(l>>4)*8+j; half h covers dims h*32..h*32+31
    s16x8 xb[4][2];
    float xnorm[4];
    #pragma unroll
    for (int v = 0; v < 4; ++v) {
        const float4* xp = (const float4*)(inp + (size_t)(vecbase + v * 16 + l15) * DIM);
        float4 a0 = xp[g * 2], a1 = xp[g * 2 + 1];
        float4 a2 = xp[8 + g * 2], a3 = xp[8 + g * 2 + 1];
        float f0[8] = {a0.x, a0.y, a0.z, a0.w, a1.x, a1.y, a1.z, a1.w};
        float f1[8] = {a2.x, a2.y, a2.z, a2.w, a3.x, a3.y, a3.z, a3.w};
        float xn = 0.f;
        unsigned w0[4], w1[4];
        #pragma unroll
        for (int p = 0; p < 4; ++p) {
            xn = fmaf(f0[2*p], f0[2*p], xn);
            xn = fmaf(f0[2*p+1], f0[2*p+1], xn);
            xn = fmaf(f1[2*p], f1[2*p], xn);
            xn = fmaf(f1[2*p+1], f1[2*p+1], xn);
            unsigned r0, r1;
            asm("v_cvt_pk_bf16_f32 %0, %1, %2" : "=v"(r0) : "v"(f0[2*p]), "v"(f0[2*p+1]));
            asm("v_cvt_pk_bf16_f32 %0, %1, %2" : "=v"(r1) : "v"(f1[2*p]), "v"(f1[2*p+1]));
            w0[p] = r0; w1[p] = r1;
        }
        xb[v][0] = *(const s16x8*)w0;
        xb[v][1] = *(const s16x8*)w1;
        xnorm[v] = xn;
    }

    float best[4] = {3.4e38f, 3.4e38f, 3.4e38f, 3.4e38f};

    // ---- K sweep: this wave covers codes [wip*512, wip*512+512) = 32 tiles ----
    const s16x8* Ap  = (const s16x8*)cbA + (size_t)(wip * 64) * 64 + lane;
    const float* cnp = cnf + wip * 512 + gi;

    #pragma unroll 2
    for (int t = 0; t < 32; ++t) {
        s16x8 A0 = Ap[0];
        s16x8 A1 = Ap[64];
        f32x4 cn4 = *(const f32x4*)cnp;      // acc init = ||c||^2

        f32x4 acc[4];
        #pragma unroll
        for (int v = 0; v < 4; ++v) acc[v] = cn4;
        #pragma unroll
        for (int v = 0; v < 4; ++v) acc[v] = MFMA16(A0, xb[v][0], acc[v]);
        #pragma unroll
        for (int v = 0; v < 4; ++v) acc[v] = MFMA16(A1, xb[v][1], acc[v]);

        int kb = wip * 512 + (t << 4) + gi;  // code index base for this lane-group
        #pragma unroll
        for (int v = 0; v < 4; ++v) {
            // (bits & ~1023) | idx  ->  v_and_or_b32 per candidate
            float p0 = __uint_as_float((__float_as_uint(acc[v][0]) & 0xFFFFFC00u) | (unsigned)(kb));
            float p1 = __uint_as_float((__float_as_uint(acc[v][1]) & 0xFFFFFC00u) | (unsigned)(kb + 1));
            float p2 = __uint_as_float((__float_as_uint(acc[v][2]) & 0xFFFFFC00u) | (unsigned)(kb + 2));
            float p3 = __uint_as_float((__float_as_uint(acc[v][3]) & 0xFFFFFC00u) | (unsigned)(kb + 3));
            best[v] = fminf(fminf(best[v], p0), fminf(fminf(p1, p2), p3));
        }
        Ap  += 128;
        cnp += 16;
    }

    // ---- reduce across the 4 lane groups; also finish ||x||^2 ----
    #pragma unroll
    for (int v = 0; v < 4; ++v) {
        best[v] = fminf(best[v], __shfl_xor(best[v], 16));
        best[v] = fminf(best[v], __shfl_xor(best[v], 32));
        xnorm[v] += __shfl_xor(xnorm[v], 16);
        xnorm[v] += __shfl_xor(xnorm[v], 32);
    }

    // ---- combine the two codebook halves across the wave pair via LDS ----
    __shared__ float sb[2][2][4][16];
    if (lane < 16) {
        #pragma unroll
        for (int v = 0; v < 4; ++v) sb[pair][wip][v][lane] = best[v];
    }
    __syncthreads();
    int bidx[4];
    #pragma unroll
    for (int v = 0; v < 4; ++v) {
        best[v] = fminf(best[v], sb[pair][wip ^ 1][v][l15]);
        bidx[v] = (int)(__float_as_uint(best[v]) & 1023u);
    }

    // ---- epilogue, split across the pair: wave wip owns v = wip*2, wip*2+1 ----
    float4* ob4 = (float4*)(out + (size_t)vecbase * DIM);
    float ls = 0.0f;
    #pragma unroll
    for (int vv = 0; vv < 2; ++vv) {
        int v = wip * 2 + vv;
        #pragma unroll
        for (int i = 0; i < 4; ++i) {
            int wv = i * 4 + g;
            int bk = __shfl(bidx[v], wv);
            float4 q = ((const float4*)(cb + (size_t)bk * DIM))[l15];
            ob4[(v * 16 + wv) * 16 + l15] = q;
        }
        if (g == 0) {
            atomicAdd(&counts[bidx[v]], 1u);
            ls += best[v] + xnorm[v];    // min distance = score + ||x||^2 (err ~1e-6)
        }
    }
    double dsum = (double)ls;
    #pragma unroll
    for (int off = 32; off > 0; off >>= 1) dsum += __shfl_xor(dsum, off);
    if (lane == 0) atomicAdd(loss_sum, dsum);
}

__global__ __launch_bounds__(256) void vq_finalize(float* __restrict__ out,
                                                   const double* __restrict__ loss_sum,
                                                   const unsigned int* __restrict__ counts) {
    __shared__ double red[256];
    double h = 0.0;
    for (int k = threadIdx.x; k < KCB; k += 256) {
        double p = (double)counts[k] / (double)NVEC;
        h += p * log(p + 1e-10);
    }
    red[threadIdx.x] = h;
    __syncthreads();
    for (int s = 128; s > 0; s >>= 1) {
        if (threadIdx.x < s) red[threadIdx.x] += red[threadIdx.x + s];
        __syncthreads();
    }
    if (threadIdx.x == 0) {
        out[(size_t)NVEC * DIM]     = (float)(0.25 * (*loss_sum) / (double)((size_t)NVEC * DIM));
        out[(size_t)NVEC * DIM + 1] = (float)exp(-red[0]);
    }
}

extern "C" void kernel_launch(void* const* d_in, const int* in_sizes, int n_in,
                              void* d_out, int out_size, void* d_ws, size_t ws_size,
                              hipStream_t stream) {
    const float* inp = (const float*)d_in[0];   // (64,64,64,64) f32
    const float* cb  = (const float*)d_in[1];   // (1024,64) f32
    float* out = (float*)d_out;

    char* ws = (char*)d_ws;
    double*         loss_sum = (double*)(ws + 0);
    unsigned int*   counts   = (unsigned int*)(ws + 8);
    float*          cnf      = (float*)(ws + 4112);
    unsigned short* cbA      = (unsigned short*)(ws + 8224);

    hipMemsetAsync(ws, 0, 4112, stream);
    vq_prep<<<dim3(32), dim3(256), 0, stream>>>(cb, cbA, cnf);
    vq_main<<<dim3(NVEC / 128), dim3(256), 0, stream>>>(inp, cbA, cnf, cb, out,
                                                        loss_sum, counts);
    vq_finalize<<<dim3(1), dim3(256), 0, stream>>>(out, loss_sum, counts);
}

// Round 6
// 138.229 us; speedup vs baseline: 1.7208x; 1.4926x over previous
//
#include <hip/hip_runtime.h>

#define NVEC (64*64*64)   // 262144 vectors
#define KCB 1024          // codebook size
#define DIM 64            // codebook dim

typedef __attribute__((ext_vector_type(8))) short s16x8;   // 8 x bf16
typedef __attribute__((ext_vector_type(4))) float f32x4;

#define MFMA16(A, B, C) __builtin_amdgcn_mfma_f32_16x16x32_bf16((A), (B), (C), 0, 0, 0)

// ws layout (bytes):
//      0 : uint counts[1024]            (ends 4096, pad to 4112)
//   4112 : float cnf[1024]              (ends 8208; +64B prefetch over-read spills
//                                        harmlessly into cbA head)
//   8224 : ushort cbA[64][2][64][8]     A-frag layout of bf16(-2c), 131072 B, ends 139296
//          (+2 KB prefetch over-read pad: 139296..141344 is reserved, value-irrelevant)
// 141344 : pad to 141568
// 141568 : float wave_partials[8192]    (ends 174336) -- per-wave loss, NO atomics

__global__ __launch_bounds__(256) void vq_prep(const float* __restrict__ cb,
                                               unsigned short* __restrict__ cbA,
                                               float* __restrict__ cnf) {
    int q = blockIdx.x * 256 + threadIdx.x;      // 0..8191
    int t = q >> 7;                               // code tile 0..63
    int h = (q >> 6) & 1;                         // k-half 0..1
    int l = q & 63;                               // lane slot
    int m = t * 16 + (l & 15);                    // code row
    int d0 = h * 32 + ((l >> 4) & 3) * 8;         // first dim of this lane's 8
    const float* row = cb + (size_t)m * DIM + d0;
    unsigned short* dst = cbA + (size_t)q * 8;
    #pragma unroll
    for (int j = 0; j < 8; ++j) {
        float f = -2.0f * row[j];
        unsigned u = __float_as_uint(f);
        dst[j] = (unsigned short)((u + 0x7fffu + ((u >> 16) & 1u)) >> 16);  // RNE bf16
    }
    if (q < KCB) {
        const float* r2 = cb + (size_t)q * DIM;
        double s = 0.0;
        for (int d = 0; d < DIM; ++d) { double c = (double)r2[d]; s = fma(c, c, s); }
        cnf[q] = (float)s;
    }
}

__global__ __launch_bounds__(256) void vq_main(const float* __restrict__ inp,
                                               const unsigned short* __restrict__ cbA,
                                               const float* __restrict__ cnf,
                                               const float* __restrict__ cb,
                                               float* __restrict__ out,
                                               float* __restrict__ partials,
                                               unsigned int* __restrict__ counts) {
    const int tid  = threadIdx.x;
    const int lane = tid & 63;
    const int w    = tid >> 6;        // wave 0..3, fully independent (no barriers)
    const int l15  = lane & 15;
    const int g    = lane >> 4;
    const int gi   = g * 4;
    const int vecbase = blockIdx.x * 128 + w * 32;   // 32 vectors per wave

    // ---- load 32 vectors, convert to bf16 B-frags, accumulate ||x||^2 ----
    // B[k][n]: lane l holds n=l&15, k=(l>>4)*8+j; half h covers dims h*32..h*32+31
    s16x8 xb[2][2];
    float xnorm[2];
    #pragma unroll
    for (int v = 0; v < 2; ++v) {
        const float4* xp = (const float4*)(inp + (size_t)(vecbase + v * 16 + l15) * DIM);
        float4 a0 = xp[g * 2], a1 = xp[g * 2 + 1];
        float4 a2 = xp[8 + g * 2], a3 = xp[8 + g * 2 + 1];
        float f0[8] = {a0.x, a0.y, a0.z, a0.w, a1.x, a1.y, a1.z, a1.w};
        float f1[8] = {a2.x, a2.y, a2.z, a2.w, a3.x, a3.y, a3.z, a3.w};
        float xn = 0.f;
        unsigned w0[4], w1[4];
        #pragma unroll
        for (int p = 0; p < 4; ++p) {
            xn = fmaf(f0[2*p], f0[2*p], xn);
            xn = fmaf(f0[2*p+1], f0[2*p+1], xn);
            xn = fmaf(f1[2*p], f1[2*p], xn);
            xn = fmaf(f1[2*p+1], f1[2*p+1], xn);
            unsigned r0, r1;
            asm("v_cvt_pk_bf16_f32 %0, %1, %2" : "=v"(r0) : "v"(f0[2*p]), "v"(f0[2*p+1]));
            asm("v_cvt_pk_bf16_f32 %0, %1, %2" : "=v"(r1) : "v"(f1[2*p]), "v"(f1[2*p+1]));
            w0[p] = r0; w1[p] = r1;
        }
        xb[v][0] = *(const s16x8*)w0;
        xb[v][1] = *(const s16x8*)w1;
        xnorm[v] = xn;
    }

    // ---- full-K sweep (64 tiles) with one-iter register prefetch ----
    const s16x8* Ap  = (const s16x8*)cbA + lane;
    const float* cnp = cnf + gi;

    s16x8 A0 = Ap[0];
    s16x8 A1 = Ap[64];
    f32x4 cn4 = *(const f32x4*)cnp;

    float best0 = 3.4e38f, best1 = 3.4e38f;

    #pragma unroll 2
    for (int t = 0; t < 64; ++t) {
        s16x8 B0 = A0, B1 = A1;
        f32x4 c4 = cn4;
        Ap  += 128;
        cnp += 16;
        A0  = Ap[0];                     // prefetch next tile (t=63: pad over-read)
        A1  = Ap[64];
        cn4 = *(const f32x4*)cnp;

        f32x4 acc0 = c4, acc1 = c4;      // acc init = ||c||^2
        acc0 = MFMA16(B0, xb[0][0], acc0);
        acc1 = MFMA16(B0, xb[1][0], acc1);
        acc0 = MFMA16(B1, xb[0][1], acc0);
        acc1 = MFMA16(B1, xb[1][1], acc1);

        int kb = (t << 4) + gi;
        {   // v = 0
            float p0 = __uint_as_float((__float_as_uint(acc0[0]) & 0xFFFFFC00u) | (unsigned)(kb));
            float p1 = __uint_as_float((__float_as_uint(acc0[1]) & 0xFFFFFC00u) | (unsigned)(kb + 1));
            float p2 = __uint_as_float((__float_as_uint(acc0[2]) & 0xFFFFFC00u) | (unsigned)(kb + 2));
            float p3 = __uint_as_float((__float_as_uint(acc0[3]) & 0xFFFFFC00u) | (unsigned)(kb + 3));
            best0 = fminf(fminf(best0, fminf(p0, p1)), fminf(p2, p3));
        }
        {   // v = 1
            float p0 = __uint_as_float((__float_as_uint(acc1[0]) & 0xFFFFFC00u) | (unsigned)(kb));
            float p1 = __uint_as_float((__float_as_uint(acc1[1]) & 0xFFFFFC00u) | (unsigned)(kb + 1));
            float p2 = __uint_as_float((__float_as_uint(acc1[2]) & 0xFFFFFC00u) | (unsigned)(kb + 2));
            float p3 = __uint_as_float((__float_as_uint(acc1[3]) & 0xFFFFFC00u) | (unsigned)(kb + 3));
            best1 = fminf(fminf(best1, fminf(p0, p1)), fminf(p2, p3));
        }
    }

    // ---- reduce across the 4 lane groups (codes split by g); finish ||x||^2 ----
    float best[2] = {best0, best1};
    int bidx[2];
    #pragma unroll
    for (int v = 0; v < 2; ++v) {
        best[v] = fminf(best[v], __shfl_xor(best[v], 16));
        best[v] = fminf(best[v], __shfl_xor(best[v], 32));
        xnorm[v] += __shfl_xor(xnorm[v], 16);
        xnorm[v] += __shfl_xor(xnorm[v], 32);
        bidx[v] = (int)(__float_as_uint(best[v]) & 1023u);
    }

    // ---- coalesced output write: wave region = 32 vectors = 8 KB contiguous ----
    float4* ob4 = (float4*)(out + (size_t)vecbase * DIM);
    float ls = 0.0f;
    #pragma unroll
    for (int v = 0; v < 2; ++v) {
        #pragma unroll
        for (int i = 0; i < 4; ++i) {
            int wv = i * 4 + g;
            int bk = __shfl(bidx[v], wv);
            float4 q = ((const float4*)(cb + (size_t)bk * DIM))[l15];
            ob4[(v * 16 + wv) * 16 + l15] = q;
        }
        if (g == 0) {
            atomicAdd(&counts[bidx[v]], 1u);          // 1024 distinct addrs, low contention
            ls += best[v] + xnorm[v];                 // min dist = score + ||x||^2
        }
    }

    // ---- per-wave loss partial -> private slot (NO atomic, NO barrier) ----
    #pragma unroll
    for (int off = 32; off > 0; off >>= 1) ls += __shfl_xor(ls, off);
    if (lane == 0) partials[blockIdx.x * 4 + w] = ls;
}

__global__ __launch_bounds__(256) void vq_finalize(float* __restrict__ out,
                                                   const float* __restrict__ partials,
                                                   const unsigned int* __restrict__ counts) {
    __shared__ double red[256];
    // sum 8192 wave partials
    double s = 0.0;
    for (int i = threadIdx.x; i < 8192; i += 256) s += (double)partials[i];
    // entropy over counts
    double h = 0.0;
    for (int k = threadIdx.x; k < KCB; k += 256) {
        double p = (double)counts[k] / (double)NVEC;
        h += p * log(p + 1e-10);
    }
    red[threadIdx.x] = s;
    __syncthreads();
    for (int t = 128; t > 0; t >>= 1) {
        if (threadIdx.x < t) red[threadIdx.x] += red[threadIdx.x + t];
        __syncthreads();
    }
    double loss_tot = red[0];
    __syncthreads();
    red[threadIdx.x] = h;
    __syncthreads();
    for (int t = 128; t > 0; t >>= 1) {
        if (threadIdx.x < t) red[threadIdx.x] += red[threadIdx.x + t];
        __syncthreads();
    }
    if (threadIdx.x == 0) {
        out[(size_t)NVEC * DIM]     = (float)(0.25 * loss_tot / (double)((size_t)NVEC * DIM));
        out[(size_t)NVEC * DIM + 1] = (float)exp(-red[0]);
    }
}

extern "C" void kernel_launch(void* const* d_in, const int* in_sizes, int n_in,
                              void* d_out, int out_size, void* d_ws, size_t ws_size,
                              hipStream_t stream) {
    const float* inp = (const float*)d_in[0];   // (64,64,64,64) f32
    const float* cb  = (const float*)d_in[1];   // (1024,64) f32
    float* out = (float*)d_out;

    char* ws = (char*)d_ws;
    unsigned int*   counts   = (unsigned int*)(ws + 0);
    float*          cnf      = (float*)(ws + 4112);
    unsigned short* cbA      = (unsigned short*)(ws + 8224);
    float*          partials = (float*)(ws + 141568);

    hipMemsetAsync(ws, 0, 4096, stream);   // counts only
    vq_prep<<<dim3(32), dim3(256), 0, stream>>>(cb, cbA, cnf);
    vq_main<<<dim3(NVEC / 128), dim3(256), 0, stream>>>(inp, cbA, cnf, cb, out,
                                                        partials, counts);
    vq_finalize<<<dim3(1), dim3(256), 0, stream>>>(out, partials, counts);
}

// Round 7
// 124.329 us; speedup vs baseline: 1.9132x; 1.1118x over previous
//
#include <hip/hip_runtime.h>

#define NVEC (64*64*64)   // 262144 vectors
#define KCB 1024          // codebook size
#define DIM 64            // codebook dim

typedef __attribute__((ext_vector_type(8))) short s16x8;   // 8 x bf16
typedef __attribute__((ext_vector_type(4))) float f32x4;

#define MFMA16(A, B, C) __builtin_amdgcn_mfma_f32_16x16x32_bf16((A), (B), (C), 0, 0, 0)

// ws layout (bytes):
//      0 : uint counts[1024]            (ends 4096, pad to 4112)
//   4112 : float cnf[1024]              (ends 8208, pad to 8224)
//   8224 : ushort cbA[64][2][64][8]     A-frag layout of bf16(-2c), 131072 B, ends 139296
// 141568 : float wave_partials[8192]    (ends 174336) -- per-wave loss, NO atomics

__global__ __launch_bounds__(256) void vq_prep(const float* __restrict__ cb,
                                               unsigned short* __restrict__ cbA,
                                               float* __restrict__ cnf) {
    int q = blockIdx.x * 256 + threadIdx.x;      // 0..8191
    int t = q >> 7;                               // code tile 0..63
    int h = (q >> 6) & 1;                         // k-half 0..1
    int l = q & 63;                               // lane slot
    int m = t * 16 + (l & 15);                    // code row
    int d0 = h * 32 + ((l >> 4) & 3) * 8;         // first dim of this lane's 8
    const float* row = cb + (size_t)m * DIM + d0;
    unsigned short* dst = cbA + (size_t)q * 8;
    #pragma unroll
    for (int j = 0; j < 8; ++j) {
        float f = -2.0f * row[j];
        unsigned u = __float_as_uint(f);
        dst[j] = (unsigned short)((u + 0x7fffu + ((u >> 16) & 1u)) >> 16);  // RNE bf16
    }
    if (q < KCB) {
        const float* r2 = cb + (size_t)q * DIM;
        double s = 0.0;
        for (int d = 0; d < DIM; ++d) { double c = (double)r2[d]; s = fma(c, c, s); }
        cnf[q] = (float)s;
    }
}

__global__ __launch_bounds__(256) void vq_main(const float* __restrict__ inp,
                                               const unsigned short* __restrict__ cbA,
                                               const float* __restrict__ cnf,
                                               const float* __restrict__ cb,
                                               float* __restrict__ out,
                                               float* __restrict__ partials,
                                               unsigned int* __restrict__ counts) {
    // LDS: double-buffered codebook chunks (4 tiles = 8KB each) + staged cnf
    __shared__ unsigned short bufS[2][4096];   // 2 x 8KB
    __shared__ float cnS[KCB];                 // 4KB

    const int tid  = threadIdx.x;
    const int lane = tid & 63;
    const int w    = tid >> 6;        // wave 0..3
    const int l15  = lane & 15;
    const int g    = lane >> 4;
    const int gi   = g * 4;
    const int vecbase = blockIdx.x * 128 + w * 32;   // 32 vectors per wave

    const int4* __restrict__ gA = (const int4*)cbA;  // 16B frag units: [row*64 + lane]

    // ---- stage chunk 0 + cnf; then load x while staging is in flight ----
    int4 s0 = gA[(2 * w) * 64 + lane];
    int4 s1 = gA[(2 * w + 1) * 64 + lane];
    float4 cnl = ((const float4*)cnf)[tid];

    // ---- load 32 vectors, convert to bf16 B-frags, accumulate ||x||^2 ----
    // B[k][n]: lane l holds n=l&15, k=(l>>4)*8+j; half h covers dims h*32..h*32+31
    s16x8 xb[2][2];
    float xnorm[2];
    #pragma unroll
    for (int v = 0; v < 2; ++v) {
        const float4* xp = (const float4*)(inp + (size_t)(vecbase + v * 16 + l15) * DIM);
        float4 a0 = xp[g * 2], a1 = xp[g * 2 + 1];
        float4 a2 = xp[8 + g * 2], a3 = xp[8 + g * 2 + 1];
        float f0[8] = {a0.x, a0.y, a0.z, a0.w, a1.x, a1.y, a1.z, a1.w};
        float f1[8] = {a2.x, a2.y, a2.z, a2.w, a3.x, a3.y, a3.z, a3.w};
        float xn = 0.f;
        unsigned w0[4], w1[4];
        #pragma unroll
        for (int p = 0; p < 4; ++p) {
            xn = fmaf(f0[2*p], f0[2*p], xn);
            xn = fmaf(f0[2*p+1], f0[2*p+1], xn);
            xn = fmaf(f1[2*p], f1[2*p], xn);
            xn = fmaf(f1[2*p+1], f1[2*p+1], xn);
            unsigned r0, r1;
            asm("v_cvt_pk_bf16_f32 %0, %1, %2" : "=v"(r0) : "v"(f0[2*p]), "v"(f0[2*p+1]));
            asm("v_cvt_pk_bf16_f32 %0, %1, %2" : "=v"(r1) : "v"(f1[2*p]), "v"(f1[2*p+1]));
            w0[p] = r0; w1[p] = r1;
        }
        xb[v][0] = *(const s16x8*)w0;
        xb[v][1] = *(const s16x8*)w1;
        xnorm[v] = xn;
    }

    // commit chunk-0 staging + cnf to LDS
    ((int4*)bufS[0])[(2 * w) * 64 + lane] = s0;
    ((int4*)bufS[0])[(2 * w + 1) * 64 + lane] = s1;
    ((float4*)cnS)[tid] = cnl;
    __syncthreads();

    float best0 = 3.4e38f, best1 = 3.4e38f;

    // ---- 16 chunks x 4 tiles; double-buffered, one barrier per chunk ----
    for (int c = 0; c < 16; ++c) {
        const int cur = c & 1;
        // issue next chunk's global loads BEFORE compute (latency hides under MFMA)
        int4 n0 = {}, n1 = {};
        const bool have = (c < 15);
        if (have) {
            int rb = (c + 1) * 8;
            n0 = gA[(rb + 2 * w) * 64 + lane];
            n1 = gA[(rb + 2 * w + 1) * 64 + lane];
        }

        const s16x8* bf = (const s16x8*)bufS[cur];   // [row*64 + lane]
        #pragma unroll
        for (int tt = 0; tt < 4; ++tt) {
            s16x8 A0 = bf[(tt * 2) * 64 + lane];
            s16x8 A1 = bf[(tt * 2 + 1) * 64 + lane];
            int t = c * 4 + tt;
            f32x4 cn4 = *(const f32x4*)(cnS + t * 16 + gi);

            f32x4 acc0 = cn4, acc1 = cn4;            // acc init = ||c||^2
            acc0 = MFMA16(A0, xb[0][0], acc0);
            acc1 = MFMA16(A0, xb[1][0], acc1);
            acc0 = MFMA16(A1, xb[0][1], acc0);
            acc1 = MFMA16(A1, xb[1][1], acc1);

            int kb = (t << 4) + gi;
            {   // v = 0
                float p0 = __uint_as_float((__float_as_uint(acc0[0]) & 0xFFFFFC00u) | (unsigned)(kb));
                float p1 = __uint_as_float((__float_as_uint(acc0[1]) & 0xFFFFFC00u) | (unsigned)(kb + 1));
                float p2 = __uint_as_float((__float_as_uint(acc0[2]) & 0xFFFFFC00u) | (unsigned)(kb + 2));
                float p3 = __uint_as_float((__float_as_uint(acc0[3]) & 0xFFFFFC00u) | (unsigned)(kb + 3));
                best0 = fminf(fminf(best0, fminf(p0, p1)), fminf(p2, p3));
            }
            {   // v = 1
                float p0 = __uint_as_float((__float_as_uint(acc1[0]) & 0xFFFFFC00u) | (unsigned)(kb));
                float p1 = __uint_as_float((__float_as_uint(acc1[1]) & 0xFFFFFC00u) | (unsigned)(kb + 1));
                float p2 = __uint_as_float((__float_as_uint(acc1[2]) & 0xFFFFFC00u) | (unsigned)(kb + 2));
                float p3 = __uint_as_float((__float_as_uint(acc1[3]) & 0xFFFFFC00u) | (unsigned)(kb + 3));
                best1 = fminf(fminf(best1, fminf(p0, p1)), fminf(p2, p3));
            }
        }

        // commit staged chunk to the other buffer, then one barrier
        if (have) {
            ((int4*)bufS[cur ^ 1])[(2 * w) * 64 + lane] = n0;
            ((int4*)bufS[cur ^ 1])[(2 * w + 1) * 64 + lane] = n1;
        }
        __syncthreads();
    }

    // ---- reduce across the 4 lane groups (codes split by g); finish ||x||^2 ----
    float best[2] = {best0, best1};
    int bidx[2];
    #pragma unroll
    for (int v = 0; v < 2; ++v) {
        best[v] = fminf(best[v], __shfl_xor(best[v], 16));
        best[v] = fminf(best[v], __shfl_xor(best[v], 32));
        xnorm[v] += __shfl_xor(xnorm[v], 16);
        xnorm[v] += __shfl_xor(xnorm[v], 32);
        bidx[v] = (int)(__float_as_uint(best[v]) & 1023u);
    }

    // ---- coalesced output write: wave region = 32 vectors = 8 KB contiguous ----
    float4* ob4 = (float4*)(out + (size_t)vecbase * DIM);
    float ls = 0.0f;
    #pragma unroll
    for (int v = 0; v < 2; ++v) {
        #pragma unroll
        for (int i = 0; i < 4; ++i) {
            int wv = i * 4 + g;
            int bk = __shfl(bidx[v], wv);
            float4 q = ((const float4*)(cb + (size_t)bk * DIM))[l15];
            ob4[(v * 16 + wv) * 16 + l15] = q;
        }
        if (g == 0) {
            atomicAdd(&counts[bidx[v]], 1u);          // 1024 distinct addrs, low contention
            ls += best[v] + xnorm[v];                 // min dist = score + ||x||^2
        }
    }

    // ---- per-wave loss partial -> private slot (NO atomic) ----
    #pragma unroll
    for (int off = 32; off > 0; off >>= 1) ls += __shfl_xor(ls, off);
    if (lane == 0) partials[blockIdx.x * 4 + w] = ls;
}

__global__ __launch_bounds__(256) void vq_finalize(float* __restrict__ out,
                                                   const float* __restrict__ partials,
                                                   const unsigned int* __restrict__ counts) {
    __shared__ double red[256];
    double s = 0.0;
    for (int i = threadIdx.x; i < 8192; i += 256) s += (double)partials[i];
    double h = 0.0;
    for (int k = threadIdx.x; k < KCB; k += 256) {
        double p = (double)counts[k] / (double)NVEC;
        h += p * log(p + 1e-10);
    }
    red[threadIdx.x] = s;
    __syncthreads();
    for (int t = 128; t > 0; t >>= 1) {
        if (threadIdx.x < t) red[threadIdx.x] += red[threadIdx.x + t];
        __syncthreads();
    }
    double loss_tot = red[0];
    __syncthreads();
    red[threadIdx.x] = h;
    __syncthreads();
    for (int t = 128; t > 0; t >>= 1) {
        if (threadIdx.x < t) red[threadIdx.x] += red[threadIdx.x + t];
        __syncthreads();
    }
    if (threadIdx.x == 0) {
        out[(size_t)NVEC * DIM]     = (float)(0.25 * loss_tot / (double)((size_t)NVEC * DIM));
        out[(size_t)NVEC * DIM + 1] = (float)exp(-red[0]);
    }
}

extern "C" void kernel_launch(void* const* d_in, const int* in_sizes, int n_in,
                              void* d_out, int out_size, void* d_ws, size_t ws_size,
                              hipStream_t stream) {
    const float* inp = (const float*)d_in[0];   // (64,64,64,64) f32
    const float* cb  = (const float*)d_in[1];   // (1024,64) f32
    float* out = (float*)d_out;

    char* ws = (char*)d_ws;
    unsigned int*   counts   = (unsigned int*)(ws + 0);
    float*          cnf      = (float*)(ws + 4112);
    unsigned short* cbA      = (unsigned short*)(ws + 8224);
    float*          partials = (float*)(ws + 141568);

    hipMemsetAsync(ws, 0, 4096, stream);   // counts only
    vq_prep<<<dim3(32), dim3(256), 0, stream>>>(cb, cbA, cnf);
    vq_main<<<dim3(NVEC / 128), dim3(256), 0, stream>>>(inp, cbA, cnf, cb, out,
                                                        partials, counts);
    vq_finalize<<<dim3(1), dim3(256), 0, stream>>>(out, partials, counts);
}

// Round 8
// 117.260 us; speedup vs baseline: 2.0286x; 1.0603x over previous
//
#include <hip/hip_runtime.h>

#define NVEC (64*64*64)   // 262144 vectors
#define KCB 1024          // codebook size
#define DIM 64            // codebook dim

typedef __attribute__((ext_vector_type(8))) short s16x8;   // 8 x bf16
typedef __attribute__((ext_vector_type(4))) float f32x4;

#define MFMA16(A, B, C) __builtin_amdgcn_mfma_f32_16x16x32_bf16((A), (B), (C), 0, 0, 0)

// ws layout (bytes):
//      0 : uint counts[1024]            (ends 4096, pad to 4112)
//   4112 : float cnf[1024]              (ends 8208, pad to 8224)
//   8224 : ushort cbA[64][2][64][8]     A-frag layout of bf16(-2c), 131072 B, ends 139296
// 141568 : float wave_partials[4096]    (ends 157952) -- per-wave loss, NO atomics

__global__ __launch_bounds__(256) void vq_prep(const float* __restrict__ cb,
                                               unsigned short* __restrict__ cbA,
                                               float* __restrict__ cnf,
                                               unsigned int* __restrict__ counts) {
    int q = blockIdx.x * 256 + threadIdx.x;      // 0..8191
    if (q < 256) ((int4*)counts)[q] = int4{0, 0, 0, 0};   // fold memset into prep
    int t = q >> 7;                               // code tile 0..63
    int h = (q >> 6) & 1;                         // k-half 0..1
    int l = q & 63;                               // lane slot
    int m = t * 16 + (l & 15);                    // code row
    int d0 = h * 32 + ((l >> 4) & 3) * 8;         // first dim of this lane's 8
    const float* row = cb + (size_t)m * DIM + d0;
    unsigned short* dst = cbA + (size_t)q * 8;
    #pragma unroll
    for (int j = 0; j < 8; ++j) {
        float f = -2.0f * row[j];
        unsigned u = __float_as_uint(f);
        dst[j] = (unsigned short)((u + 0x7fffu + ((u >> 16) & 1u)) >> 16);  // RNE bf16
    }
    if (q < KCB) {
        const float* r2 = cb + (size_t)q * DIM;
        double s = 0.0;
        for (int d = 0; d < DIM; ++d) { double c = (double)r2[d]; s = fma(c, c, s); }
        cnf[q] = (float)s;
    }
}

__global__ __launch_bounds__(256, 4) void vq_main(const float* __restrict__ inp,
                                                  const unsigned short* __restrict__ cbA,
                                                  const float* __restrict__ cnf,
                                                  const float* __restrict__ cb,
                                                  float* __restrict__ out,
                                                  float* __restrict__ partials,
                                                  unsigned int* __restrict__ counts) {
    // LDS: double-buffered codebook chunks (4 tiles = 8KB each) + staged cnf = 20KB
    __shared__ unsigned short bufS[2][4096];
    __shared__ float cnS[KCB];

    const int tid  = threadIdx.x;
    const int lane = tid & 63;
    const int w    = tid >> 6;        // wave 0..3
    const int l15  = lane & 15;
    const int g    = lane >> 4;
    const int gi   = g * 4;
    const int vecbase = blockIdx.x * 256 + w * 64;   // 64 vectors per wave

    const int4* __restrict__ gA = (const int4*)cbA;  // 16B frag units: [row*64 + lane]

    // ---- issue chunk-0 staging + cnf loads; x-loads overlap their latency ----
    int4 s0 = gA[(2 * w) * 64 + lane];
    int4 s1 = gA[(2 * w + 1) * 64 + lane];
    float4 cnl = ((const float4*)cnf)[tid];

    // ---- load 64 vectors, convert to bf16 B-frags, accumulate ||x||^2 ----
    // B[k][n]: lane l holds n=l&15, k=(l>>4)*8+j; half h covers dims h*32..h*32+31
    s16x8 xb[4][2];
    float xnorm[4];
    #pragma unroll
    for (int v = 0; v < 4; ++v) {
        const float4* xp = (const float4*)(inp + (size_t)(vecbase + v * 16 + l15) * DIM);
        float4 a0 = xp[g * 2], a1 = xp[g * 2 + 1];
        float4 a2 = xp[8 + g * 2], a3 = xp[8 + g * 2 + 1];
        float f0[8] = {a0.x, a0.y, a0.z, a0.w, a1.x, a1.y, a1.z, a1.w};
        float f1[8] = {a2.x, a2.y, a2.z, a2.w, a3.x, a3.y, a3.z, a3.w};
        float xn = 0.f;
        unsigned w0[4], w1[4];
        #pragma unroll
        for (int p = 0; p < 4; ++p) {
            xn = fmaf(f0[2*p], f0[2*p], xn);
            xn = fmaf(f0[2*p+1], f0[2*p+1], xn);
            xn = fmaf(f1[2*p], f1[2*p], xn);
            xn = fmaf(f1[2*p+1], f1[2*p+1], xn);
            unsigned r0, r1;
            asm("v_cvt_pk_bf16_f32 %0, %1, %2" : "=v"(r0) : "v"(f0[2*p]), "v"(f0[2*p+1]));
            asm("v_cvt_pk_bf16_f32 %0, %1, %2" : "=v"(r1) : "v"(f1[2*p]), "v"(f1[2*p+1]));
            w0[p] = r0; w1[p] = r1;
        }
        xb[v][0] = *(const s16x8*)w0;
        xb[v][1] = *(const s16x8*)w1;
        xnorm[v] = xn;
    }

    // commit chunk-0 staging + cnf to LDS
    ((int4*)bufS[0])[(2 * w) * 64 + lane] = s0;
    ((int4*)bufS[0])[(2 * w + 1) * 64 + lane] = s1;
    ((float4*)cnS)[tid] = cnl;
    __syncthreads();

    float best[4] = {3.4e38f, 3.4e38f, 3.4e38f, 3.4e38f};

    // ---- 16 chunks x 4 tiles; double-buffered, one barrier per chunk ----
    for (int c = 0; c < 16; ++c) {
        const int cur = c & 1;
        // issue next chunk's global loads BEFORE compute (latency hides under MFMA)
        int4 n0 = {}, n1 = {};
        const bool have = (c < 15);
        if (have) {
            int rb = (c + 1) * 8;
            n0 = gA[(rb + 2 * w) * 64 + lane];
            n1 = gA[(rb + 2 * w + 1) * 64 + lane];
        }

        const s16x8* bf = (const s16x8*)bufS[cur];   // [row*64 + lane]
        #pragma unroll
        for (int tt = 0; tt < 4; ++tt) {
            s16x8 A0 = bf[(tt * 2) * 64 + lane];
            s16x8 A1 = bf[(tt * 2 + 1) * 64 + lane];
            int t = c * 4 + tt;
            f32x4 cn4 = *(const f32x4*)(cnS + t * 16 + gi);

            f32x4 acc[4];
            #pragma unroll
            for (int v = 0; v < 4; ++v) acc[v] = cn4;       // acc init = ||c||^2
            #pragma unroll
            for (int v = 0; v < 4; ++v) acc[v] = MFMA16(A0, xb[v][0], acc[v]);
            #pragma unroll
            for (int v = 0; v < 4; ++v) acc[v] = MFMA16(A1, xb[v][1], acc[v]);

            int kb = (t << 4) + gi;
            #pragma unroll
            for (int v = 0; v < 4; ++v) {
                float p0 = __uint_as_float((__float_as_uint(acc[v][0]) & 0xFFFFFC00u) | (unsigned)(kb));
                float p1 = __uint_as_float((__float_as_uint(acc[v][1]) & 0xFFFFFC00u) | (unsigned)(kb + 1));
                float p2 = __uint_as_float((__float_as_uint(acc[v][2]) & 0xFFFFFC00u) | (unsigned)(kb + 2));
                float p3 = __uint_as_float((__float_as_uint(acc[v][3]) & 0xFFFFFC00u) | (unsigned)(kb + 3));
                float p01 = fminf(p0, p1), p23 = fminf(p2, p3);
                best[v] = fminf(fminf(p01, p23), best[v]);   // min3-shaped tree
            }
        }

        // commit staged chunk to the other buffer, then one barrier
        if (have) {
            ((int4*)bufS[cur ^ 1])[(2 * w) * 64 + lane] = n0;
            ((int4*)bufS[cur ^ 1])[(2 * w + 1) * 64 + lane] = n1;
        }
        __syncthreads();
    }

    // ---- reduce across the 4 lane groups (codes split by g); finish ||x||^2 ----
    int bidx[4];
    #pragma unroll
    for (int v = 0; v < 4; ++v) {
        best[v] = fminf(best[v], __shfl_xor(best[v], 16));
        best[v] = fminf(best[v], __shfl_xor(best[v], 32));
        xnorm[v] += __shfl_xor(xnorm[v], 16);
        xnorm[v] += __shfl_xor(xnorm[v], 32);
        bidx[v] = (int)(__float_as_uint(best[v]) & 1023u);
    }

    // ---- coalesced output write: wave region = 64 vectors = 16 KB contiguous ----
    float4* ob4 = (float4*)(out + (size_t)vecbase * DIM);
    float ls = 0.0f;
    #pragma unroll
    for (int v = 0; v < 4; ++v) {
        #pragma unroll
        for (int i = 0; i < 4; ++i) {
            int wv = i * 4 + g;
            int bk = __shfl(bidx[v], wv);
            float4 q = ((const float4*)(cb + (size_t)bk * DIM))[l15];
            ob4[(v * 16 + wv) * 16 + l15] = q;
        }
        if (g == 0) {
            atomicAdd(&counts[bidx[v]], 1u);   // 16 lanes, 16 distinct vectors/addresses
            ls += best[v] + xnorm[v];          // min dist = score + ||x||^2
        }
    }

    // ---- per-wave loss partial -> private slot (NO atomic) ----
    #pragma unroll
    for (int off = 32; off > 0; off >>= 1) ls += __shfl_xor(ls, off);
    if (lane == 0) partials[blockIdx.x * 4 + w] = ls;
}

__global__ __launch_bounds__(256) void vq_finalize(float* __restrict__ out,
                                                   const float* __restrict__ partials,
                                                   const unsigned int* __restrict__ counts) {
    __shared__ double red[256];
    double s = 0.0;
    for (int i = threadIdx.x; i < 4096; i += 256) s += (double)partials[i];
    double h = 0.0;
    for (int k = threadIdx.x; k < KCB; k += 256) {
        double p = (double)counts[k] / (double)NVEC;
        h += p * log(p + 1e-10);
    }
    red[threadIdx.x] = s;
    __syncthreads();
    for (int t = 128; t > 0; t >>= 1) {
        if (threadIdx.x < t) red[threadIdx.x] += red[threadIdx.x + t];
        __syncthreads();
    }
    double loss_tot = red[0];
    __syncthreads();
    red[threadIdx.x] = h;
    __syncthreads();
    for (int t = 128; t > 0; t >>= 1) {
        if (threadIdx.x < t) red[threadIdx.x] += red[threadIdx.x + t];
        __syncthreads();
    }
    if (threadIdx.x == 0) {
        out[(size_t)NVEC * DIM]     = (float)(0.25 * loss_tot / (double)((size_t)NVEC * DIM));
        out[(size_t)NVEC * DIM + 1] = (float)exp(-red[0]);
    }
}

extern "C" void kernel_launch(void* const* d_in, const int* in_sizes, int n_in,
                              void* d_out, int out_size, void* d_ws, size_t ws_size,
                              hipStream_t stream) {
    const float* inp = (const float*)d_in[0];   // (64,64,64,64) f32
    const float* cb  = (const float*)d_in[1];   // (1024,64) f32
    float* out = (float*)d_out;

    char* ws = (char*)d_ws;
    unsigned int*   counts   = (unsigned int*)(ws + 0);
    float*          cnf      = (float*)(ws + 4112);
    unsigned short* cbA      = (unsigned short*)(ws + 8224);
    float*          partials = (float*)(ws + 141568);

    vq_prep<<<dim3(32), dim3(256), 0, stream>>>(cb, cbA, cnf, counts);
    vq_main<<<dim3(NVEC / 256), dim3(256), 0, stream>>>(inp, cbA, cnf, cb, out,
                                                        partials, counts);
    vq_finalize<<<dim3(1), dim3(256), 0, stream>>>(out, partials, counts);
}